// Round 1
// baseline (120.255 us; speedup 1.0000x reference)
//
#include <hip/hip_runtime.h>
#include <hip/hip_bf16.h>

#define NL 2048   // languages
#define DE 64     // embedding dim
#define VV 2048   // vocab
#define BI 64     // i-tile rows
#define BJ 32     // j-tile cols
#define NTI (NL / BI)             // 32 i-tiles
#define NTJ (NL / BJ)             // 64 j-tiles
#define NBLK 1056                 // sum_{bi=0}^{31} (64 - 2*bi)
#define STI 68    // Eit [dim][i] stride
#define STJ 36    // Ejt [dim][j] stride

// ws layout (no memset needed — every word is written before read):
// [0:1024)      float pmax[256]
// [1024:9216)   int   perm[2048]
// [9216:17408)  int   sids[2048]
// [17408:21632) float psum[1056]
// [21632:25856) uint  pcnt[1056]
// [25856:25860) uint  ticket   (zeroed by prep block 256; used by loss last-block)

// Blocks 0..255: block-local max over map_dist slice -> pmax[b] (plain store).
// Block 256: counting-sort 2048 ids in LDS; also zeroes the finalize ticket.
__global__ __launch_bounds__(1024) void prep_kernel(const int* __restrict__ ids,
                                                    const float4* __restrict__ m4,
                                                    float* __restrict__ pmax,
                                                    int* __restrict__ perm,
                                                    int* __restrict__ sids,
                                                    unsigned* __restrict__ ticket) {
    const int t = threadIdx.x;
    const int lane = t & 63, wave = t >> 6;
    const int b = blockIdx.x;

    if (b < 256) {
        const float4* p = m4 + (size_t)b * 4096;
        const float4 x0 = p[t], x1 = p[t + 1024], x2 = p[t + 2048], x3 = p[t + 3072];
        float v = fmaxf(fmaxf(fmaxf(x0.x, x0.y), fmaxf(x0.z, x0.w)),
                        fmaxf(fmaxf(x1.x, x1.y), fmaxf(x1.z, x1.w)));
        v = fmaxf(v, fmaxf(fmaxf(x2.x, x2.y), fmaxf(x2.z, x2.w)));
        v = fmaxf(v, fmaxf(fmaxf(x3.x, x3.y), fmaxf(x3.z, x3.w)));
        #pragma unroll
        for (int o = 32; o > 0; o >>= 1)
            v = fmaxf(v, __shfl_down(v, o));
        __shared__ float wl[16];
        if (lane == 0) wl[wave] = v;
        __syncthreads();
        if (t == 0) {
            float m = wl[0];
            #pragma unroll
            for (int i = 1; i < 16; ++i) m = fmaxf(m, wl[i]);
            pmax[b] = m;
        }
    } else {
        __shared__ unsigned hist[VV];
        __shared__ unsigned offs[VV];
        __shared__ unsigned wtot[16];
        __shared__ unsigned wexc[16];
        if (t == 0) *ticket = 0u;      // reset finalize ticket for this iteration
        hist[2 * t] = 0u; hist[2 * t + 1] = 0u;
        __syncthreads();
        const int id0 = ids[2 * t], id1 = ids[2 * t + 1];
        atomicAdd(&hist[id0], 1u);
        atomicAdd(&hist[id1], 1u);
        __syncthreads();
        const unsigned h0 = hist[2 * t], h1 = hist[2 * t + 1];
        const unsigned s = h0 + h1;
        unsigned ps = s;
        #pragma unroll
        for (int o = 1; o < 64; o <<= 1) {
            unsigned u = __shfl_up(ps, o);
            if (lane >= o) ps += u;
        }
        if (lane == 63) wtot[wave] = ps;
        __syncthreads();
        if (wave == 0 && lane < 16) {
            unsigned v = wtot[lane];
            unsigned pv = v;
            #pragma unroll
            for (int o = 1; o < 16; o <<= 1) {
                unsigned u = __shfl_up(pv, o);
                if (lane >= o) pv += u;
            }
            wexc[lane] = pv - v;
        }
        __syncthreads();
        const unsigned ex = wexc[wave] + ps - s;
        offs[2 * t]     = ex;
        offs[2 * t + 1] = ex + h0;
        __syncthreads();
        unsigned p0 = atomicAdd(&offs[id0], 1u);
        perm[p0] = 2 * t;     sids[p0] = id0;
        unsigned p1 = atomicAdd(&offs[id1], 1u);
        perm[p1] = 2 * t + 1; sids[p1] = id1;
    }
}

__global__ __launch_bounds__(256) void loss_kernel(
    const float* __restrict__ emb,
    const float* __restrict__ tree, const float* __restrict__ mapd,
    const int* __restrict__ perm, const int* __restrict__ sids,
    const float* __restrict__ pmax,
    float* __restrict__ psum, unsigned* __restrict__ pcnt,
    unsigned* __restrict__ ticket, float* __restrict__ out)
{
    const int t = threadIdx.x;

    // Rect-tile decode: L -> (bi, bj), bj in [2*bi, 64). cum(bi) = 65*bi - bi^2.
    const int L = blockIdx.x;
    int bi = (int)((65.0f - sqrtf(4225.0f - 4.0f * (float)L)) * 0.5f);
    if (bi > NTI - 1) bi = NTI - 1;
    if (bi < 0) bi = 0;
    while (65 * bi - bi * bi > L) --bi;
    while (65 * (bi + 1) - (bi + 1) * (bi + 1) <= L) ++bi;
    const int bj = 2 * bi + (L - (65 * bi - bi * bi));

    // Tiles transposed [dim][idx]; all k-loop reads broadcast-heavy & conflict-free.
    __shared__ __align__(16) float Eit[DE][STI];
    __shared__ __align__(16) float Ejt[DE][STJ];
    __shared__ int idi[BI];
    __shared__ int idj[BJ];
    __shared__ float wm[4];

    // max partials: independent load issued first
    float pv = pmax[t];

    // ---- Stage: Eit 64 rows (4 f4/thread), Ejt 32 rows (2 f4/thread) ----
    {
        const int r  = t & 63;
        const int c0 = (t >> 6) << 4;   // 0,16,32,48
        const int gi = perm[bi * BI + r];
        const float4* pa = (const float4*)(emb + (size_t)gi * DE + c0);
        float4 a0 = pa[0], a1 = pa[1], a2 = pa[2], a3 = pa[3];
        Eit[c0 + 0][r]  = a0.x; Eit[c0 + 1][r]  = a0.y; Eit[c0 + 2][r]  = a0.z; Eit[c0 + 3][r]  = a0.w;
        Eit[c0 + 4][r]  = a1.x; Eit[c0 + 5][r]  = a1.y; Eit[c0 + 6][r]  = a1.z; Eit[c0 + 7][r]  = a1.w;
        Eit[c0 + 8][r]  = a2.x; Eit[c0 + 9][r]  = a2.y; Eit[c0 + 10][r] = a2.z; Eit[c0 + 11][r] = a2.w;
        Eit[c0 + 12][r] = a3.x; Eit[c0 + 13][r] = a3.y; Eit[c0 + 14][r] = a3.z; Eit[c0 + 15][r] = a3.w;

        const int rj  = t & 31;
        const int cj0 = (t >> 5) << 3;  // 0,8,...,56
        const int gj = perm[bj * BJ + rj];
        const float4* pb = (const float4*)(emb + (size_t)gj * DE + cj0);
        float4 b0 = pb[0], b1 = pb[1];
        Ejt[cj0 + 0][rj] = b0.x; Ejt[cj0 + 1][rj] = b0.y; Ejt[cj0 + 2][rj] = b0.z; Ejt[cj0 + 3][rj] = b0.w;
        Ejt[cj0 + 4][rj] = b1.x; Ejt[cj0 + 5][rj] = b1.y; Ejt[cj0 + 6][rj] = b1.z; Ejt[cj0 + 7][rj] = b1.w;

        if (t < BI)            idi[t] = sids[bi * BI + t];
        else if (t < BI + BJ)  idj[t - BI] = sids[bj * BJ + (t - BI)];
    }
    #pragma unroll
    for (int o = 32; o > 0; o >>= 1)
        pv = fmaxf(pv, __shfl_down(pv, o));
    if ((t & 63) == 0) wm[t >> 6] = pv;
    __syncthreads();

    const float inv = 1.0f / fmaxf(fmaxf(wm[0], wm[1]), fmaxf(wm[2], wm[3]));

    const int i0 = (t >> 4) * 4;   // 16 groups x 4 rows
    const int j0 = (t & 15) * 2;   // 16 groups x 2 cols

    // ---- Hoisted metric gathers (8 pairs): hide under the k-loop ----
    int ia[4], ja[2];
    #pragma unroll
    for (int s = 0; s < 4; ++s) ia[s] = idi[i0 + s];
    #pragma unroll
    for (int c = 0; c < 2; ++c) ja[c] = idj[j0 + c];
    float tg[4][2], mg[4][2];
    #pragma unroll
    for (int s = 0; s < 4; ++s)
        #pragma unroll
        for (int c = 0; c < 2; ++c) {
            const int off = ia[s] * VV + ja[c];
            tg[s][c] = tree[off];
            mg[s][c] = mapd[off];
        }

    float acc[4][2];
    #pragma unroll
    for (int s = 0; s < 4; ++s) { acc[s][0] = 0.0f; acc[s][1] = 0.0f; }

    // unroll 2 = proven no-spill regime
    #pragma unroll 2
    for (int k = 0; k < 16; ++k) {
        #pragma unroll
        for (int q = 0; q < 4; ++q) {
            const int d = 4 * k + q;
            const float4 a = *(const float4*)&Eit[d][i0];
            const float2 b = *(const float2*)&Ejt[d][j0];
            acc[0][0] += fabsf(a.x - b.x); acc[0][1] += fabsf(a.x - b.y);
            acc[1][0] += fabsf(a.y - b.x); acc[1][1] += fabsf(a.y - b.y);
            acc[2][0] += fabsf(a.z - b.x); acc[2][1] += fabsf(a.z - b.y);
            acc[3][0] += fabsf(a.w - b.x); acc[3][1] += fabsf(a.w - b.y);
        }
    }

    // ---- Epilogue: per-pair dedup (pos_i < pos_j -> weight 2; ids mask) ----
    float pp = 0.0f;
    unsigned cnt = 0;
    #pragma unroll
    for (int s = 0; s < 4; ++s) {
        const int posi = bi * BI + i0 + s;
        #pragma unroll
        for (int c = 0; c < 2; ++c) {
            const int posj = bj * BJ + j0 + c;
            if (posi < posj && ia[s] != ja[c]) {
                const float metric = (tg[s][c] + mg[s][c] * inv) * 0.5f;
                pp += 2.0f * fabsf(acc[s][c] * (1.0f / (float)DE) - metric);
                cnt += 2u;
            }
        }
    }

    #pragma unroll
    for (int o = 32; o > 0; o >>= 1) {
        pp  += __shfl_down(pp, o);
        cnt += __shfl_down(cnt, o);
    }
    __shared__ float    wsum_l[4];
    __shared__ unsigned wcnt_l[4];
    __shared__ unsigned lastflag;
    if ((t & 63) == 0) { wsum_l[t >> 6] = pp; wcnt_l[t >> 6] = cnt; }
    __syncthreads();
    if (t == 0) {
        psum[L] = wsum_l[0] + wsum_l[1] + wsum_l[2] + wsum_l[3];  // plain stores, no atomics
        pcnt[L] = wcnt_l[0] + wcnt_l[1] + wcnt_l[2] + wcnt_l[3];
        __threadfence();                                  // release psum/pcnt to device scope
        const unsigned tk = atomicAdd(ticket, 1u);        // device-scope ticket
        lastflag = (tk == (unsigned)(NBLK - 1)) ? 1u : 0u;
    }
    __syncthreads();

    // ---- Fused finalize: the last block to finish reduces all partials ----
    if (lastflag) {
        __threadfence();                                  // acquire: see others' psum/pcnt
        double s = 0.0;
        unsigned c = 0;
        for (int i = t; i < NBLK; i += 256) { s += (double)psum[i]; c += pcnt[i]; }
        #pragma unroll
        for (int o = 32; o > 0; o >>= 1) {
            s += __shfl_down(s, o);
            c += __shfl_down(c, o);
        }
        __shared__ double   sl[4];
        __shared__ unsigned cl[4];
        if ((t & 63) == 0) { sl[t >> 6] = s; cl[t >> 6] = c; }
        __syncthreads();
        if (t == 0) {
            const double   S = sl[0] + sl[1] + sl[2] + sl[3];
            const unsigned C = cl[0] + cl[1] + cl[2] + cl[3];
            out[0] = (float)(S / (double)C);
        }
    }
}

extern "C" void kernel_launch(void* const* d_in, const int* in_sizes, int n_in,
                              void* d_out, int out_size, void* d_ws, size_t ws_size,
                              hipStream_t stream) {
    const int*   ids  = (const int*)d_in[0];
    const float* emb  = (const float*)d_in[1];
    const float* tree = (const float*)d_in[2];
    const float* mapd = (const float*)d_in[3];
    float* out = (float*)d_out;

    float*    pmax   = (float*)d_ws;                        // 256 floats
    int*      perm   = (int*)((char*)d_ws + 1024);          // 2048 ints
    int*      sids   = (int*)((char*)d_ws + 9216);          // 2048 ints
    float*    psum   = (float*)((char*)d_ws + 17408);       // 1056 floats
    unsigned* pcnt   = (unsigned*)((char*)d_ws + 21632);    // 1056 uints
    unsigned* ticket = (unsigned*)((char*)d_ws + 25856);    // 1 uint

    prep_kernel<<<257, 1024, 0, stream>>>(ids, (const float4*)mapd, pmax, perm, sids, ticket);

    loss_kernel<<<NBLK, 256, 0, stream>>>(emb, tree, mapd, perm, sids, pmax,
                                          psum, pcnt, ticket, out);
}

// Round 2
// 98.109 us; speedup vs baseline: 1.2257x; 1.2257x over previous
//
#include <hip/hip_runtime.h>
#include <hip/hip_bf16.h>

#define NL 2048   // languages
#define DE 64     // embedding dim
#define VV 2048   // vocab
#define BI 64     // i-tile rows
#define BJ 32     // j-tile cols
#define NTI (NL / BI)             // 32 i-tiles
#define NTJ (NL / BJ)             // 64 j-tiles
#define NBLK 1056                 // sum_{bi=0}^{31} (64 - 2*bi)
#define STI 66    // Eit [dim][i] stride (float2 reads -> +2 pad keeps 8B align)
#define STJ 36    // Ejt [dim][j] stride

// ws layout (no memset needed — every word is written before read):
// [0:1024)      float pmax[256]
// [1024:9216)   int   perm[2048]
// [9216:17408)  int   sids[2048]
// [17408:21632) float psum[1056]
// [21632:25856) uint  pcnt[1056]

// Blocks 0..255: block-local max over map_dist slice -> pmax[b] (plain store).
// Block 256: counting-sort 2048 ids in LDS.
__global__ __launch_bounds__(1024) void prep_kernel(const int* __restrict__ ids,
                                                    const float4* __restrict__ m4,
                                                    float* __restrict__ pmax,
                                                    int* __restrict__ perm,
                                                    int* __restrict__ sids) {
    const int t = threadIdx.x;
    const int lane = t & 63, wave = t >> 6;
    const int b = blockIdx.x;

    if (b < 256) {
        const float4* p = m4 + (size_t)b * 4096;
        const float4 x0 = p[t], x1 = p[t + 1024], x2 = p[t + 2048], x3 = p[t + 3072];
        float v = fmaxf(fmaxf(fmaxf(x0.x, x0.y), fmaxf(x0.z, x0.w)),
                        fmaxf(fmaxf(x1.x, x1.y), fmaxf(x1.z, x1.w)));
        v = fmaxf(v, fmaxf(fmaxf(x2.x, x2.y), fmaxf(x2.z, x2.w)));
        v = fmaxf(v, fmaxf(fmaxf(x3.x, x3.y), fmaxf(x3.z, x3.w)));
        #pragma unroll
        for (int o = 32; o > 0; o >>= 1)
            v = fmaxf(v, __shfl_down(v, o));
        __shared__ float wl[16];
        if (lane == 0) wl[wave] = v;
        __syncthreads();
        if (t == 0) {
            float m = wl[0];
            #pragma unroll
            for (int i = 1; i < 16; ++i) m = fmaxf(m, wl[i]);
            pmax[b] = m;
        }
    } else {
        __shared__ unsigned hist[VV];
        __shared__ unsigned offs[VV];
        __shared__ unsigned wtot[16];
        __shared__ unsigned wexc[16];
        hist[2 * t] = 0u; hist[2 * t + 1] = 0u;
        __syncthreads();
        const int id0 = ids[2 * t], id1 = ids[2 * t + 1];
        atomicAdd(&hist[id0], 1u);
        atomicAdd(&hist[id1], 1u);
        __syncthreads();
        const unsigned h0 = hist[2 * t], h1 = hist[2 * t + 1];
        const unsigned s = h0 + h1;
        unsigned ps = s;
        #pragma unroll
        for (int o = 1; o < 64; o <<= 1) {
            unsigned u = __shfl_up(ps, o);
            if (lane >= o) ps += u;
        }
        if (lane == 63) wtot[wave] = ps;
        __syncthreads();
        if (wave == 0 && lane < 16) {
            unsigned v = wtot[lane];
            unsigned pv = v;
            #pragma unroll
            for (int o = 1; o < 16; o <<= 1) {
                unsigned u = __shfl_up(pv, o);
                if (lane >= o) pv += u;
            }
            wexc[lane] = pv - v;
        }
        __syncthreads();
        const unsigned ex = wexc[wave] + ps - s;
        offs[2 * t]     = ex;
        offs[2 * t + 1] = ex + h0;
        __syncthreads();
        unsigned p0 = atomicAdd(&offs[id0], 1u);
        perm[p0] = 2 * t;     sids[p0] = id0;
        unsigned p1 = atomicAdd(&offs[id1], 1u);
        perm[p1] = 2 * t + 1; sids[p1] = id1;
    }
}

// 512 threads/block: 8 waves -> 32 waves/CU residency cap (was 16).
// Per thread: 2x2 output pairs; gathers issued at kernel top from global sids
// (no LDS/barrier dependency) so their cold-HBM latency hides under staging+k-loop.
__global__ __launch_bounds__(512, 8) void loss_kernel(
    const float* __restrict__ emb,
    const float* __restrict__ tree, const float* __restrict__ mapd,
    const int* __restrict__ perm, const int* __restrict__ sids,
    const float* __restrict__ pmax,
    float* __restrict__ psum, unsigned* __restrict__ pcnt)
{
    const int t = threadIdx.x;

    // Rect-tile decode: L -> (bi, bj), bj in [2*bi, 64). cum(bi) = 65*bi - bi^2.
    const int L = blockIdx.x;
    int bi = (int)((65.0f - sqrtf(4225.0f - 4.0f * (float)L)) * 0.5f);
    if (bi > NTI - 1) bi = NTI - 1;
    if (bi < 0) bi = 0;
    while (65 * bi - bi * bi > L) --bi;
    while (65 * (bi + 1) - (bi + 1) * (bi + 1) <= L) ++bi;
    const int bj = 2 * bi + (L - (65 * bi - bi * bi));

    const int i0 = (t >> 4) * 2;   // 32 groups x 2 rows (covers 64)
    const int j0 = (t & 15) * 2;   // 16 groups x 2 cols (covers 32)

    // ---- Earliest possible: ids direct from global, then the 8 cold gathers ----
    int ia[2], ja[2];
    ia[0] = sids[bi * BI + i0];     ia[1] = sids[bi * BI + i0 + 1];
    ja[0] = sids[bj * BJ + j0];     ja[1] = sids[bj * BJ + j0 + 1];
    float tg[2][2], mg[2][2];
    #pragma unroll
    for (int s = 0; s < 2; ++s)
        #pragma unroll
        for (int c = 0; c < 2; ++c) {
            const int off = ia[s] * VV + ja[c];
            tg[s][c] = tree[off];
            mg[s][c] = mapd[off];
        }

    // Tiles transposed [dim][idx]; all k-loop reads broadcast-heavy & conflict-free.
    __shared__ __align__(16) float Eit[DE][STI];
    __shared__ __align__(16) float Ejt[DE][STJ];
    __shared__ float wm[8];

    // max partials: independent load issued early
    float pv = pmax[t & 255];

    // ---- Stage: Eit 64 rows (2 f4/thread), Ejt 32 rows (1 f4/thread) ----
    {
        const int r  = t & 63;
        const int c0 = (t >> 6) << 3;   // 0,8,...,56
        const int gi = perm[bi * BI + r];
        const float4* pa = (const float4*)(emb + (size_t)gi * DE + c0);
        float4 a0 = pa[0], a1 = pa[1];
        Eit[c0 + 0][r] = a0.x; Eit[c0 + 1][r] = a0.y; Eit[c0 + 2][r] = a0.z; Eit[c0 + 3][r] = a0.w;
        Eit[c0 + 4][r] = a1.x; Eit[c0 + 5][r] = a1.y; Eit[c0 + 6][r] = a1.z; Eit[c0 + 7][r] = a1.w;

        const int rj  = t & 31;
        const int cj0 = (t >> 5) << 2;  // 0,4,...,60
        const int gj = perm[bj * BJ + rj];
        const float4* pb = (const float4*)(emb + (size_t)gj * DE + cj0);
        float4 b0 = pb[0];
        Ejt[cj0 + 0][rj] = b0.x; Ejt[cj0 + 1][rj] = b0.y; Ejt[cj0 + 2][rj] = b0.z; Ejt[cj0 + 3][rj] = b0.w;
    }
    #pragma unroll
    for (int o = 32; o > 0; o >>= 1)
        pv = fmaxf(pv, __shfl_down(pv, o));
    if ((t & 63) == 0) wm[t >> 6] = pv;
    __syncthreads();

    float bm = fmaxf(fmaxf(wm[0], wm[1]), fmaxf(wm[2], wm[3]));
    bm = fmaxf(bm, fmaxf(fmaxf(wm[4], wm[5]), fmaxf(wm[6], wm[7])));
    const float inv = 1.0f / bm;

    float acc[2][2];
    acc[0][0] = 0.0f; acc[0][1] = 0.0f; acc[1][0] = 0.0f; acc[1][1] = 0.0f;

    // unroll 2 = proven no-spill regime
    #pragma unroll 2
    for (int k = 0; k < 16; ++k) {
        #pragma unroll
        for (int q = 0; q < 4; ++q) {
            const int d = 4 * k + q;
            const float2 a = *(const float2*)&Eit[d][i0];
            const float2 b = *(const float2*)&Ejt[d][j0];
            acc[0][0] += fabsf(a.x - b.x); acc[0][1] += fabsf(a.x - b.y);
            acc[1][0] += fabsf(a.y - b.x); acc[1][1] += fabsf(a.y - b.y);
        }
    }

    // ---- Epilogue: per-pair dedup (pos_i < pos_j -> weight 2; ids mask) ----
    float pp = 0.0f;
    unsigned cnt = 0;
    #pragma unroll
    for (int s = 0; s < 2; ++s) {
        const int posi = bi * BI + i0 + s;
        #pragma unroll
        for (int c = 0; c < 2; ++c) {
            const int posj = bj * BJ + j0 + c;
            if (posi < posj && ia[s] != ja[c]) {
                const float metric = (tg[s][c] + mg[s][c] * inv) * 0.5f;
                pp += 2.0f * fabsf(acc[s][c] * (1.0f / (float)DE) - metric);
                cnt += 2u;
            }
        }
    }

    #pragma unroll
    for (int o = 32; o > 0; o >>= 1) {
        pp  += __shfl_down(pp, o);
        cnt += __shfl_down(cnt, o);
    }
    __shared__ float    wsum_l[8];
    __shared__ unsigned wcnt_l[8];
    if ((t & 63) == 0) { wsum_l[t >> 6] = pp; wcnt_l[t >> 6] = cnt; }
    __syncthreads();
    if (t == 0) {
        float    S = 0.0f;
        unsigned C = 0u;
        #pragma unroll
        for (int w = 0; w < 8; ++w) { S += wsum_l[w]; C += wcnt_l[w]; }
        psum[L] = S;   // plain stores, no atomics
        pcnt[L] = C;
    }
}

__global__ __launch_bounds__(1024) void finalize_kernel(const float* __restrict__ psum,
                                                        const unsigned* __restrict__ pcnt,
                                                        float* __restrict__ out) {
    const int t = threadIdx.x;
    const int lane = t & 63, wave = t >> 6;
    double s = 0.0;
    unsigned c = 0;
    for (int i = t; i < NBLK; i += 1024) { s += (double)psum[i]; c += pcnt[i]; }
    #pragma unroll
    for (int o = 32; o > 0; o >>= 1) {
        s += __shfl_down(s, o);
        c += __shfl_down(c, o);
    }
    __shared__ double   sl[16];
    __shared__ unsigned cl[16];
    if (lane == 0) { sl[wave] = s; cl[wave] = c; }
    __syncthreads();
    if (t == 0) {
        double   S = sl[0];
        unsigned C = cl[0];
        #pragma unroll
        for (int i = 1; i < 16; ++i) { S += sl[i]; C += cl[i]; }
        out[0] = (float)(S / (double)C);
    }
}

extern "C" void kernel_launch(void* const* d_in, const int* in_sizes, int n_in,
                              void* d_out, int out_size, void* d_ws, size_t ws_size,
                              hipStream_t stream) {
    const int*   ids  = (const int*)d_in[0];
    const float* emb  = (const float*)d_in[1];
    const float* tree = (const float*)d_in[2];
    const float* mapd = (const float*)d_in[3];
    float* out = (float*)d_out;

    float*    pmax = (float*)d_ws;                        // 256 floats
    int*      perm = (int*)((char*)d_ws + 1024);          // 2048 ints
    int*      sids = (int*)((char*)d_ws + 9216);          // 2048 ints
    float*    psum = (float*)((char*)d_ws + 17408);       // 1056 floats
    unsigned* pcnt = (unsigned*)((char*)d_ws + 21632);    // 1056 uints

    prep_kernel<<<257, 1024, 0, stream>>>(ids, (const float4*)mapd, pmax, perm, sids);

    loss_kernel<<<NBLK, 512, 0, stream>>>(emb, tree, mapd, perm, sids, pmax, psum, pcnt);

    finalize_kernel<<<1, 1024, 0, stream>>>(psum, pcnt, out);
}